// Round 8
// baseline (248.733 us; speedup 1.0000x reference)
//
#include <hip/hip_runtime.h>
#include <hip/hip_cooperative_groups.h>
#include <math.h>

namespace cg = cooperative_groups;

#define NSHOT 5
#define WAY 32
#define DIM 640
#define NQ 4096
#define RNEAR 10

// ---- workspace layout (float offsets) — R6-proven footprint (~1.13 MB) ----
constexpr int OFF_PROTOS = 0;        // 32*640
constexpr int OFF_QPART  = 20480;    // 128*640 column partial sums
constexpr int OFF_C      = 102400;   // 32
constexpr int OFF_XVEC   = 102432;   // 32*640 (proto_p)
constexpr int OFF_DIS    = 122912;   // 32*4096
constexpr int OFF_S      = 253984;   // 32
constexpr int OFF_U      = 254016;   // 32
constexpr int OFF_NID    = 254048;   // 32*10
constexpr int OFF_TP     = 254368;   // 32*640 (test_proto)
constexpr int OFF_NIDX   = 274848;   // 32*10 ints
constexpr int OFF_Q2D    = 275200;   // double[4096] (even -> 8B aligned)
constexpr int OFF_X2D    = 283392;   // double[32] (proto_p norms^2)
constexpr int OFF_X2D2   = 283456;   // double[32] (test_proto norms^2)

__device__ __forceinline__ double wave_sum_d(double v) {
#pragma unroll
  for (int o = 32; o > 0; o >>= 1) v += __shfl_down(v, o, 64);
  return v;
}

__device__ __forceinline__ double dist_hyp(double c, double xdotq, double u2, double q2) {
  const double EPSd = 1e-5;
  double sc = sqrt(c);
  double nq = sqrt(q2);
  double nf = fmax(nq, EPSd);
  double th = tanh(sc * nf);
  double al = th / (sc * nf);
  double ny = fmax(al * nq, EPSd);
  double mx = 0.999 / sc;
  if (ny > mx) al *= mx / ny;
  double y2 = al * al * q2;
  double uy = -al * xdotq;
  double A = 1.0 + 2.0 * c * uy + c * y2;
  double B = 1.0 - c * u2;
  double den = fmax(1.0 + 2.0 * c * uy + c * c * u2 * y2, EPSd);
  double num2 = fmax(A * A * u2 + 2.0 * A * B * uy + B * B * y2, 0.0);
  double n = sqrt(num2) / den;
  double arg = sc * n;
  const double CLIP = (double)(1.0f - 1e-5f);
  arg = fmin(fmax(arg, 0.0), CLIP);
  return (1.0 / sc) * log((1.0 + arg) / (1.0 - arg));
}

__device__ __forceinline__ double expmap_scale(double c, double p2, double* u2out) {
  double sc = sqrt(c);
  double ntrue = sqrt(p2);
  double nf = fmax(ntrue, 1e-5);
  double th = tanh(sc * nf);
  double s0 = th / (sc * nf);
  double ny = fmax(s0 * ntrue, 1e-5);
  double mx = 0.999 / sc;
  if (ny > mx) s0 *= mx / ny;
  *u2out = s0 * s0 * p2;
  return s0;
}

struct SmemG {
  float Qs[2][16][68];
  float Xs[2][32][68];
};
struct SmemA {
  double q2w[32][4];
};
struct SmemC {
  float pr[DIM], am[DIM];
  float h1p[2][128], h1s[128];
  float h2p[4][64], h2s[64];
  float lg[5];
  double redd[4];
  double sBeta;
};
struct SmemD {
  double sredS[4], sredU[4];
  float wv[4]; int wi[4];
  int swi;
};
struct SmemE {
  float colsh[RNEAR][33];
  float rr[22];
  float qjNid[RNEAR];
  int qj[RNEAR];
  float Ssh[WAY], Ush[WAY];
  float hr[RNEAR], iw[RNEAR];
  float onw;
  double p2red[4];
  double gshd;
};
union SmemAll { SmemG g; SmemA a; SmemC c; SmemD d; SmemE e; };

// full-K 16q-tile GEMM + fused f64 distance epilogue
__device__ __forceinline__ void gemm_body(float Qs[2][16][68], float Xs[2][32][68],
                                          const float* __restrict__ X,
                                          const float* __restrict__ Qm,
                                          float* __restrict__ ws, int mode,
                                          float* __restrict__ out, int bx) {
  int t = threadIdx.x;
  int q = t & 15, wp = t >> 4;
  int q0 = bx * 16;
  int colbase = (t & 15) * 4;
  int rq = t >> 4;
  const float* qsrc  = Qm + (size_t)(q0 + rq) * DIM + colbase;
  const float* x0src = X + (size_t)rq * DIM + colbase;
  const float* x1src = X + (size_t)(16 + rq) * DIM + colbase;
  float4 qreg  = *(const float4*)(qsrc);
  float4 x0reg = *(const float4*)(x0src);
  float4 x1reg = *(const float4*)(x1src);
  *(float4*)&Qs[0][rq][colbase] = qreg;
  *(float4*)&Xs[0][rq][colbase] = x0reg;
  *(float4*)&Xs[0][16 + rq][colbase] = x1reg;
  __syncthreads();
  float acc0 = 0.f, acc1 = 0.f;
  for (int c = 0; c < 10; ++c) {
    int b = c & 1;
    if (c < 9) {
      int kc = (c + 1) * 64;
      qreg  = *(const float4*)(qsrc + kc);
      x0reg = *(const float4*)(x0src + kc);
      x1reg = *(const float4*)(x1src + kc);
    }
    const float* qrow = &Qs[b][q][0];
    const float* xr0  = &Xs[b][wp][0];
    const float* xr1  = &Xs[b][wp + 16][0];
#pragma unroll
    for (int kk = 0; kk < 64; kk += 4) {
      float4 qv = *(const float4*)(qrow + kk);
      float4 a  = *(const float4*)(xr0 + kk);
      float4 bb = *(const float4*)(xr1 + kk);
      acc0 = fmaf(a.x, qv.x, acc0);  acc0 = fmaf(a.y, qv.y, acc0);
      acc0 = fmaf(a.z, qv.z, acc0);  acc0 = fmaf(a.w, qv.w, acc0);
      acc1 = fmaf(bb.x, qv.x, acc1); acc1 = fmaf(bb.y, qv.y, acc1);
      acc1 = fmaf(bb.z, qv.z, acc1); acc1 = fmaf(bb.w, qv.w, acc1);
    }
    if (c < 9) {
      __syncthreads();
      int nb = b ^ 1;
      *(float4*)&Qs[nb][rq][colbase] = qreg;
      *(float4*)&Xs[nb][rq][colbase] = x0reg;
      *(float4*)&Xs[nb][16 + rq][colbase] = x1reg;
      __syncthreads();
    }
  }
  const double* q2d   = (const double*)(ws + OFF_Q2D);
  const double* u2arr = (const double*)(ws + (mode ? OFF_X2D2 : OFF_X2D));
  int qq = q0 + q;
  double q2 = q2d[qq];
  double d0 = dist_hyp((double)ws[OFF_C + wp],      (double)acc0, u2arr[wp],      q2);
  double d1 = dist_hyp((double)ws[OFF_C + wp + 16], (double)acc1, u2arr[wp + 16], q2);
  if (mode == 0) {
    ws[OFF_DIS + (size_t)wp * NQ + qq]        = (float)d0;
    ws[OFF_DIS + (size_t)(wp + 16) * NQ + qq] = (float)d1;
  } else {
    out[(size_t)qq * WAY + wp]      = (float)(-d0 / 16.0);
    out[(size_t)qq * WAY + wp + 16] = (float)(-d1 / 16.0);
  }
}

// ======================= cooperative mega-kernel =======================
__global__ __launch_bounds__(256) void k_mega(const float* __restrict__ shot,
                                              const float* __restrict__ Qm,
                                              const float* __restrict__ W1, const float* __restrict__ b1,
                                              const float* __restrict__ W2, const float* __restrict__ b2,
                                              const float* __restrict__ W3, const float* __restrict__ b3,
                                              const float* __restrict__ Wr1, const float* __restrict__ br1,
                                              const float* __restrict__ Wr2, const float* __restrict__ br2,
                                              float* __restrict__ ws, float* __restrict__ out) {
  __shared__ SmemAll sm;
  cg::grid_group grid = cg::this_grid();
  int b = blockIdx.x, t = threadIdx.x;
  int lane = t & 63, wid = t >> 6;   // 4 waves
  int* nidx = (int*)(ws + OFF_NIDX);

  // ===== Phase A: protos (b<32) + per-row q2 + column partials (b<128, 32 rows each) =====
  if (b < WAY) {
    for (int d = t; d < DIM; d += 256) {
      float s = 0.f;
#pragma unroll
      for (int s5 = 0; s5 < NSHOT; ++s5) s += shot[(size_t)(s5 * WAY + b) * DIM + d];
      ws[OFF_PROTOS + b * DIM + d] = s * 0.2f;
    }
  }
  if (b < 128) {
    int r0 = b * 32;
    float ca0 = 0.f, ca1 = 0.f, ca2 = 0.f;
    for (int r = 0; r < 32; ++r) {
      const float* row = Qm + (size_t)(r0 + r) * DIM;
      float x0 = row[t], x1 = row[t + 256];
      float x2 = (t < 128) ? row[t + 512] : 0.f;
      ca0 += x0; ca1 += x1; ca2 += x2;
      double sq = (double)x0 * x0 + (double)x1 * x1 + (double)x2 * x2;
      sq = wave_sum_d(sq);
      if (lane == 0) sm.a.q2w[r][wid] = sq;
    }
    __syncthreads();
    if (t < 32) {
      double s = sm.a.q2w[t][0] + sm.a.q2w[t][1] + sm.a.q2w[t][2] + sm.a.q2w[t][3];
      ((double*)(ws + OFF_Q2D))[r0 + t] = s;
    }
    ws[OFF_QPART + b * DIM + t] = ca0;
    ws[OFF_QPART + b * DIM + t + 256] = ca1;
    if (t < 128) ws[OFF_QPART + b * DIM + t + 512] = ca2;
  }
  grid.sync();

  // ===== Phase B: controller MLP (blocks 0..31) =====
  if (b < WAY) {
    double ps = 0.0;
    for (int d = t; d < DIM; d += 256) {
      float v = ws[OFF_PROTOS + b * DIM + d];
      sm.c.pr[d] = v; ps += (double)v * v;
      float qs_ = 0.f;
#pragma unroll 4
      for (int p = 0; p < 128; ++p) qs_ += ws[OFF_QPART + p * DIM + d];
      double s = (double)qs_;
      for (int w2 = 0; w2 < WAY; ++w2) s += 5.0 * (double)ws[OFF_PROTOS + w2 * DIM + d];
      sm.c.am[d] = (float)(s / 4256.0);
    }
    ps = wave_sum_d(ps);
    if (lane == 0) sm.c.redd[wid] = ps;
    __syncthreads();
    {
      int n = t & 127, s = t >> 7;       // 2 slices x 640
      const float* src = s ? sm.c.am : sm.c.pr;
      const float* Wb  = W1 + (s ? (size_t)DIM * 128 : 0);
      float acc = 0.f;
#pragma unroll 8
      for (int k = 0; k < DIM; ++k) acc = fmaf(src[k], Wb[(size_t)k * 128 + n], acc);
      sm.c.h1p[s][n] = acc;
    }
    __syncthreads();
    if (t < 128) sm.c.h1s[t] = fmaxf(sm.c.h1p[0][t] + sm.c.h1p[1][t] + b1[t], 0.f);
    __syncthreads();
    {
      int n = t & 63, s2 = t >> 6;       // 4 slices x 32
      int k0 = s2 * 32;
      float acc = 0.f;
#pragma unroll
      for (int k = 0; k < 32; ++k) acc = fmaf(sm.c.h1s[k0 + k], W2[(size_t)(k0 + k) * 64 + n], acc);
      sm.c.h2p[s2][n] = acc;
    }
    __syncthreads();
    if (t < 64) {
      float a = sm.c.h2p[0][t] + sm.c.h2p[1][t] + sm.c.h2p[2][t] + sm.c.h2p[3][t] + b2[t];
      sm.c.h2s[t] = fmaxf(a, 0.f);
    }
    __syncthreads();
    if (t < 5) {
      float a = b3[t];
      for (int k = 0; k < 64; ++k) a = fmaf(sm.c.h2s[k], W3[k * 5 + t], a);
      sm.c.lg[t] = a;
    }
    __syncthreads();
    if (t == 0) {
      double p2 = sm.c.redd[0] + sm.c.redd[1] + sm.c.redd[2] + sm.c.redd[3];
      double m = sm.c.lg[0];
      for (int i = 1; i < 5; ++i) m = fmax(m, (double)sm.c.lg[i]);
      double se = 0.0, cv = 0.0;
      for (int i = 0; i < 5; ++i) { double e = exp((double)sm.c.lg[i] - m); se += e; cv += e * 0.2 * (double)(i + 1); }
      double c = cv / se;
      ws[OFF_C + b] = (float)c;
      double u2;
      sm.c.sBeta = expmap_scale(c, p2, &u2);
      ((double*)(ws + OFF_X2D))[b] = u2;
    }
    __syncthreads();
    float beta = (float)sm.c.sBeta;
    for (int d = t; d < DIM; d += 256) ws[OFF_XVEC + b * DIM + d] = beta * sm.c.pr[d];
  }
  grid.sync();

  // ===== Phase C: GEMM1 + dist -> DIS =====
  gemm_body(sm.g.Qs, sm.g.Xs, ws + OFF_XVEC, Qm, ws, 0, out, b);
  grid.sync();

  // ===== Phase D: topk (blocks 0..31) =====
  if (b < WAY) {
    const float* base = ws + OFF_DIS + (size_t)b * NQ;
    float v[16];
    unsigned tk = 0;
    double s = 0.0;
#pragma unroll 16
    for (int i = 0; i < 16; ++i) { v[i] = base[i * 256 + t]; s += (double)v[i]; }
    double u = (t < RNEAR) ? (double)v[0] : 0.0;
    s = wave_sum_d(s);
    u = wave_sum_d(u);
    if (lane == 0) { sm.d.sredS[wid] = s; sm.d.sredU[wid] = u; }
    __syncthreads();
    if (t == 0) {
      ws[OFF_S + b] = (float)(sm.d.sredS[0] + sm.d.sredS[1] + sm.d.sredS[2] + sm.d.sredS[3]);
      ws[OFF_U + b] = (float)(sm.d.sredU[0] + sm.d.sredU[1] + sm.d.sredU[2] + sm.d.sredU[3]);
    }
    for (int r = 0; r < RNEAR; ++r) {
      float lv = INFINITY; int li = 0x7fffffff;
#pragma unroll 16
      for (int i = 0; i < 16; ++i) {
        if (!(tk & (1u << i))) {
          int qq = i * 256 + t;
          if (v[i] < lv || (v[i] == lv && qq < li)) { lv = v[i]; li = qq; }
        }
      }
#pragma unroll
      for (int o = 32; o > 0; o >>= 1) {
        float ov = __shfl_down(lv, o, 64);
        int oi = __shfl_down(li, o, 64);
        if (ov < lv || (ov == lv && oi < li)) { lv = ov; li = oi; }
      }
      if (lane == 0) { sm.d.wv[wid] = lv; sm.d.wi[wid] = li; }
      __syncthreads();
      if (t < 64) {
        float bv = (lane < 4) ? sm.d.wv[lane] : INFINITY;
        int bi = (lane < 4) ? sm.d.wi[lane] : 0x7fffffff;
#pragma unroll
        for (int o = 2; o > 0; o >>= 1) {
          float ov = __shfl_down(bv, o, 64);
          int oi = __shfl_down(bi, o, 64);
          if (ov < bv || (ov == bv && oi < bi)) { bv = ov; bi = oi; }
        }
        if (lane == 0) {
          ws[OFF_NID + b * RNEAR + r] = bv;
          nidx[b * RNEAR + r] = bi;
          sm.d.swi = bi;
        }
      }
      __syncthreads();
      int sw = sm.d.swi;
      if ((sw & 255) == t) tk |= 1u << (sw >> 8);
      __syncthreads();
    }
  }
  grid.sync();

  // ===== Phase E: refine + tmp/expmap -> TP (blocks 0..31) =====
  if (b < WAY) {
    if (t < WAY) { sm.e.Ssh[t] = ws[OFF_S + t]; sm.e.Ush[t] = ws[OFF_U + t]; }
    if (t >= 64 && t < 64 + RNEAR) {
      int j = t - 64;
      sm.e.qj[j] = nidx[b * RNEAR + j];
      sm.e.qjNid[j] = ws[OFF_NID + b * RNEAR + j];
    }
    __syncthreads();
    for (int idx = t; idx < WAY * RNEAR; idx += 256) {
      int j = idx >> 5, w2 = idx & 31;
      sm.e.colsh[j][w2] = ws[OFF_DIS + (size_t)w2 * NQ + sm.e.qj[j]];
    }
    __syncthreads();
    if (t < RNEAR) {
      double cs = 0.0, pc = 0.0;
      for (int w2 = 0; w2 < WAY; ++w2) {
        float dv = sm.e.colsh[t][w2];
        cs += dv;
        if (w2 < b) pc += dv;
      }
      sm.e.rr[t] = sm.e.qjNid[t];
      sm.e.rr[RNEAR + t] = (float)((cs - sm.e.qjNid[t]) / (double)(WAY - 1));
      sm.e.colsh[t][32] = (float)pc;
    }
    __syncthreads();
    if (t == 0) {
      double sn = 0.0; for (int j = 0; j < RNEAR; ++j) sn += sm.e.rr[j];
      double oi = ((double)sm.e.Ssh[b] - sn) / (double)(NQ - RNEAR);
      double pref = 0.0; for (int j = 0; j < b; ++j) pref += sm.e.Ssh[j];
      double suf = 0.0; for (int j = b + 1; j < WAY; ++j) suf += (double)sm.e.Ssh[j] - (double)sm.e.Ush[j];
      double spc = 0.0; for (int j = 0; j < RNEAR; ++j) spc += sm.e.colsh[j][32];
      sm.e.rr[20] = (float)oi;
      sm.e.rr[21] = (float)((pref - spc + suf) / ((double)(WAY - 1) * (double)(NQ - RNEAR)));
    }
    __syncthreads();
    if (t < RNEAR) {
      float a = br1[t];
      for (int k = 0; k < 22; ++k) a = fmaf(sm.e.rr[k], Wr1[k * RNEAR + t], a);
      sm.e.hr[t] = fmaxf(a, 0.f);
    }
    __syncthreads();
    if (t == 0) {
      double o[11];
      for (int r2 = 0; r2 < 11; ++r2) {
        float a = br2[r2];
        for (int k = 0; k < RNEAR; ++k) a = fmaf(sm.e.hr[k], Wr2[k * 11 + r2], a);
        o[r2] = a;
      }
      double m = o[0]; for (int i = 1; i < RNEAR; ++i) m = fmax(m, o[i]);
      double se = 0.0; double e[RNEAR];
      for (int i = 0; i < RNEAR; ++i) { e[i] = exp(o[i] - m); se += e[i]; }
      for (int i = 0; i < RNEAR; ++i) sm.e.iw[i] = (float)(e[i] / se);
      sm.e.onw = (float)(1.0 / (1.0 + exp(-o[10])));
    }
    __syncthreads();
    float onwv = sm.e.onw;
    float a0 = 0.f, a1 = 0.f, a2 = 0.f;
    double ls = 0.0;
    {
      int d = t;
      float wd = 0.f;
#pragma unroll
      for (int j = 0; j < RNEAR; ++j) wd = fmaf(Qm[(size_t)sm.e.qj[j] * DIM + d], sm.e.iw[j], wd);
      a0 = ws[OFF_PROTOS + b * DIM + d] * onwv + wd * (1.f - onwv);
      ls += (double)a0 * a0;
    }
    {
      int d = t + 256;
      float wd = 0.f;
#pragma unroll
      for (int j = 0; j < RNEAR; ++j) wd = fmaf(Qm[(size_t)sm.e.qj[j] * DIM + d], sm.e.iw[j], wd);
      a1 = ws[OFF_PROTOS + b * DIM + d] * onwv + wd * (1.f - onwv);
      ls += (double)a1 * a1;
    }
    if (t < 128) {
      int d = t + 512;
      float wd = 0.f;
#pragma unroll
      for (int j = 0; j < RNEAR; ++j) wd = fmaf(Qm[(size_t)sm.e.qj[j] * DIM + d], sm.e.iw[j], wd);
      a2 = ws[OFF_PROTOS + b * DIM + d] * onwv + wd * (1.f - onwv);
      ls += (double)a2 * a2;
    }
    ls = wave_sum_d(ls);
    if (lane == 0) sm.e.p2red[wid] = ls;
    __syncthreads();
    if (t == 0) {
      double p2 = sm.e.p2red[0] + sm.e.p2red[1] + sm.e.p2red[2] + sm.e.p2red[3];
      double c = (double)ws[OFF_C + b];
      double u2;
      sm.e.gshd = expmap_scale(c, p2, &u2);
      ((double*)(ws + OFF_X2D2))[b] = u2;
    }
    __syncthreads();
    float g = (float)sm.e.gshd;
    ws[OFF_TP + b * DIM + t] = g * a0;
    ws[OFF_TP + b * DIM + t + 256] = g * a1;
    if (t < 128) ws[OFF_TP + b * DIM + t + 512] = g * a2;
  }
  grid.sync();

  // ===== Phase F: GEMM2 + dist -> out =====
  gemm_body(sm.g.Qs, sm.g.Xs, ws + OFF_TP, Qm, ws, 1, out, b);
}

// ======================= R6 fallback kernels (proven, 107 µs) =======================
__global__ __launch_bounds__(640) void k_fuse1(const float* __restrict__ Qm,
                                               const float* __restrict__ shot, float* ws) {
  __shared__ double q2w[32][10];
  int b = blockIdx.x, t = threadIdx.x;
  int lane = t & 63, wid = t >> 6;
  if (b < WAY) {
    float s = 0.f;
#pragma unroll
    for (int s5 = 0; s5 < NSHOT; ++s5) s += shot[(size_t)(s5 * WAY + b) * DIM + t];
    ws[OFF_PROTOS + b * DIM + t] = s * 0.2f;
  }
  int r0 = b * 32;
  float colacc = 0.f;
  for (int r = 0; r < 32; ++r) {
    float v = Qm[(size_t)(r0 + r) * DIM + t];
    colacc += v;
    double sq = (double)v * v;
    sq = wave_sum_d(sq);
    if (lane == 0) q2w[r][wid] = sq;
  }
  ws[OFF_QPART + b * DIM + t] = colacc;
  __syncthreads();
  if (t < 32) {
    double s = 0.0;
#pragma unroll
    for (int k = 0; k < 10; ++k) s += q2w[t][k];
    ((double*)(ws + OFF_Q2D))[r0 + t] = s;
  }
}

__global__ __launch_bounds__(512) void k_ctrl(const float* __restrict__ W1, const float* __restrict__ b1,
                                              const float* __restrict__ W2, const float* __restrict__ b2,
                                              const float* __restrict__ W3, const float* __restrict__ b3,
                                              float* ws) {
  __shared__ float pr[DIM], am[DIM];
  __shared__ float h1p[4][128], h1s[128];
  __shared__ float h2p[8][64], h2s[64];
  __shared__ float lg[5];
  __shared__ double redd[8];
  __shared__ double sBeta;
  int w = blockIdx.x, t = threadIdx.x;
  double ps = 0.0;
  for (int d = t; d < DIM; d += 512) {
    float v = ws[OFF_PROTOS + w * DIM + d];
    pr[d] = v; ps += (double)v * v;
    float qs_ = 0.f;
    for (int p = 0; p < 128; ++p) qs_ += ws[OFF_QPART + p * DIM + d];
    double s = (double)qs_;
    for (int w2 = 0; w2 < WAY; ++w2) s += 5.0 * (double)ws[OFF_PROTOS + w2 * DIM + d];
    am[d] = (float)(s / 4256.0);
  }
  ps = wave_sum_d(ps);
  int lane = t & 63, wid = t >> 6;
  if (lane == 0) redd[wid] = ps;
  __syncthreads();
  {
    int n = t & 127, s = t >> 7;
    float acc = 0.f;
    if (s < 2) {
      int k0 = s * 320;
#pragma unroll 8
      for (int k = 0; k < 320; ++k) acc = fmaf(pr[k0 + k], W1[(size_t)(k0 + k) * 128 + n], acc);
    } else {
      int k0 = (s - 2) * 320;
#pragma unroll 8
      for (int k = 0; k < 320; ++k) acc = fmaf(am[k0 + k], W1[(size_t)(640 + k0 + k) * 128 + n], acc);
    }
    h1p[s][n] = acc;
  }
  __syncthreads();
  if (t < 128) h1s[t] = fmaxf(h1p[0][t] + h1p[1][t] + h1p[2][t] + h1p[3][t] + b1[t], 0.f);
  __syncthreads();
  {
    int n = t & 63, s = t >> 6;
    int k0 = s * 16;
    float acc = 0.f;
#pragma unroll
    for (int k = 0; k < 16; ++k) acc = fmaf(h1s[k0 + k], W2[(size_t)(k0 + k) * 64 + n], acc);
    h2p[s][n] = acc;
  }
  __syncthreads();
  if (t < 64) {
    float a = h2p[0][t];
#pragma unroll
    for (int s = 1; s < 8; ++s) a += h2p[s][t];
    h2s[t] = fmaxf(a + b2[t], 0.f);
  }
  __syncthreads();
  if (t < 5) {
    float a = b3[t];
    for (int k = 0; k < 64; ++k) a = fmaf(h2s[k], W3[k * 5 + t], a);
    lg[t] = a;
  }
  __syncthreads();
  if (t == 0) {
    double p2 = 0.0;
    for (int i = 0; i < 8; ++i) p2 += redd[i];
    double m = lg[0];
    for (int i = 1; i < 5; ++i) m = fmax(m, (double)lg[i]);
    double se = 0.0, cv = 0.0;
    for (int i = 0; i < 5; ++i) { double e = exp((double)lg[i] - m); se += e; cv += e * 0.2 * (double)(i + 1); }
    double c = cv / se;
    ws[OFF_C + w] = (float)c;
    double u2;
    sBeta = expmap_scale(c, p2, &u2);
    ((double*)(ws + OFF_X2D))[w] = u2;
  }
  __syncthreads();
  float beta = (float)sBeta;
  for (int d = t; d < DIM; d += 512) ws[OFF_XVEC + w * DIM + d] = beta * pr[d];
}

__global__ __launch_bounds__(256) void k_gemmdist(const float* __restrict__ X, const float* __restrict__ Qm,
                                                  float* __restrict__ ws, int mode, float* __restrict__ out) {
  __shared__ float Qs[2][16][68];
  __shared__ float Xs[2][32][68];
  gemm_body(Qs, Xs, X, Qm, ws, mode, out, blockIdx.x);
}

__global__ __launch_bounds__(1024) void k_topk(float* ws, int* nidx) {
  __shared__ double sredS[16], sredU[16];
  __shared__ float wv[16]; __shared__ int wi[16];
  __shared__ int swi;
  int w = blockIdx.x, t = threadIdx.x;
  int lane = t & 63, wid = t >> 6;
  const float* base = ws + OFF_DIS + (size_t)w * NQ;
  float v0 = base[t], v1 = base[1024 + t], v2 = base[2048 + t], v3 = base[3072 + t];
  unsigned tk = 0;
  double s = (double)v0 + (double)v1 + (double)v2 + (double)v3;
  double u = (t < RNEAR) ? (double)v0 : 0.0;
  s = wave_sum_d(s);
  u = wave_sum_d(u);
  if (lane == 0) { sredS[wid] = s; sredU[wid] = u; }
  __syncthreads();
  if (t == 0) {
    double S = 0.0, U = 0.0;
    for (int k = 0; k < 16; ++k) { S += sredS[k]; U += sredU[k]; }
    ws[OFF_S + w] = (float)S;
    ws[OFF_U + w] = (float)U;
  }
  for (int r = 0; r < RNEAR; ++r) {
    float lv = INFINITY; int li = 0x7fffffff;
    if (!(tk & 1u) && (v0 < lv || (v0 == lv && t < li)))        { lv = v0; li = t; }
    if (!(tk & 2u) && (v1 < lv || (v1 == lv && 1024 + t < li))) { lv = v1; li = 1024 + t; }
    if (!(tk & 4u) && (v2 < lv || (v2 == lv && 2048 + t < li))) { lv = v2; li = 2048 + t; }
    if (!(tk & 8u) && (v3 < lv || (v3 == lv && 3072 + t < li))) { lv = v3; li = 3072 + t; }
#pragma unroll
    for (int o = 32; o > 0; o >>= 1) {
      float ov = __shfl_down(lv, o, 64);
      int oi = __shfl_down(li, o, 64);
      if (ov < lv || (ov == lv && oi < li)) { lv = ov; li = oi; }
    }
    if (lane == 0) { wv[wid] = lv; wi[wid] = li; }
    __syncthreads();
    if (t < 64) {
      float bv = (lane < 16) ? wv[lane] : INFINITY;
      int bi = (lane < 16) ? wi[lane] : 0x7fffffff;
#pragma unroll
      for (int o = 8; o > 0; o >>= 1) {
        float ov = __shfl_down(bv, o, 64);
        int oi = __shfl_down(bi, o, 64);
        if (ov < bv || (ov == bv && oi < bi)) { bv = ov; bi = oi; }
      }
      if (lane == 0) {
        ws[OFF_NID + w * RNEAR + r] = bv;
        nidx[w * RNEAR + r] = bi;
        swi = bi;
      }
    }
    __syncthreads();
    int sw = swi;
    if ((sw & 1023) == t) tk |= 1u << (sw >> 10);
  }
}

__global__ __launch_bounds__(512) void k_reftmp(const float* __restrict__ Qm,
                                                const float* __restrict__ Wr1, const float* __restrict__ br1,
                                                const float* __restrict__ Wr2, const float* __restrict__ br2,
                                                float* ws, const int* __restrict__ nidx) {
  __shared__ float colsh[RNEAR][33];
  __shared__ float rr[22];
  __shared__ float qjNid[RNEAR];
  __shared__ int qj[RNEAR];
  __shared__ float Ssh[WAY], Ush[WAY];
  __shared__ float hr[RNEAR], iw[RNEAR];
  __shared__ float onw_sh;
  __shared__ double p2red[8];
  __shared__ double gshd;
  int w = blockIdx.x, t = threadIdx.x;
  int lane = t & 63, wid = t >> 6;
  if (t < WAY) { Ssh[t] = ws[OFF_S + t]; Ush[t] = ws[OFF_U + t]; }
  if (t >= 64 && t < 64 + RNEAR) {
    int j = t - 64;
    qj[j] = nidx[w * RNEAR + j];
    qjNid[j] = ws[OFF_NID + w * RNEAR + j];
  }
  __syncthreads();
  if (t < WAY * RNEAR) {
    int j = t >> 5, w2 = t & 31;
    colsh[j][w2] = ws[OFF_DIS + (size_t)w2 * NQ + qj[j]];
  }
  __syncthreads();
  if (t < RNEAR) {
    double cs = 0.0, pc = 0.0;
    for (int w2 = 0; w2 < WAY; ++w2) {
      float dv = colsh[t][w2];
      cs += dv;
      if (w2 < w) pc += dv;
    }
    rr[t] = qjNid[t];
    rr[RNEAR + t] = (float)((cs - qjNid[t]) / (double)(WAY - 1));
    colsh[t][32] = (float)pc;
  }
  __syncthreads();
  if (t == 0) {
    double sn = 0.0; for (int j = 0; j < RNEAR; ++j) sn += rr[j];
    double oi = ((double)Ssh[w] - sn) / (double)(NQ - RNEAR);
    double pref = 0.0; for (int j = 0; j < w; ++j) pref += Ssh[j];
    double suf = 0.0; for (int j = w + 1; j < WAY; ++j) suf += (double)Ssh[j] - (double)Ush[j];
    double spc = 0.0; for (int j = 0; j < RNEAR; ++j) spc += colsh[j][32];
    rr[20] = (float)oi;
    rr[21] = (float)((pref - spc + suf) / ((double)(WAY - 1) * (double)(NQ - RNEAR)));
  }
  __syncthreads();
  if (t < RNEAR) {
    float a = br1[t];
    for (int k = 0; k < 22; ++k) a = fmaf(rr[k], Wr1[k * RNEAR + t], a);
    hr[t] = fmaxf(a, 0.f);
  }
  __syncthreads();
  if (t == 0) {
    double o[11];
    for (int r2 = 0; r2 < 11; ++r2) {
      float a = br2[r2];
      for (int k = 0; k < RNEAR; ++k) a = fmaf(hr[k], Wr2[k * 11 + r2], a);
      o[r2] = a;
    }
    double m = o[0]; for (int i = 1; i < RNEAR; ++i) m = fmax(m, o[i]);
    double se = 0.0; double e[RNEAR];
    for (int i = 0; i < RNEAR; ++i) { e[i] = exp(o[i] - m); se += e[i]; }
    for (int i = 0; i < RNEAR; ++i) iw[i] = (float)(e[i] / se);
    onw_sh = (float)(1.0 / (1.0 + exp(-o[10])));
  }
  __syncthreads();
  float onwv = onw_sh;
  float a0 = 0.f, a1 = 0.f;
  bool has2 = (t + 512 < DIM);
  double ls = 0.0;
  {
    int d = t;
    float wd = 0.f;
#pragma unroll
    for (int j = 0; j < RNEAR; ++j) wd = fmaf(Qm[(size_t)qj[j] * DIM + d], iw[j], wd);
    a0 = ws[OFF_PROTOS + w * DIM + d] * onwv + wd * (1.f - onwv);
    ls += (double)a0 * a0;
  }
  if (has2) {
    int d = t + 512;
    float wd = 0.f;
#pragma unroll
    for (int j = 0; j < RNEAR; ++j) wd = fmaf(Qm[(size_t)qj[j] * DIM + d], iw[j], wd);
    a1 = ws[OFF_PROTOS + w * DIM + d] * onwv + wd * (1.f - onwv);
    ls += (double)a1 * a1;
  }
  ls = wave_sum_d(ls);
  if (lane == 0) p2red[wid] = ls;
  __syncthreads();
  if (t == 0) {
    double p2 = 0.0;
    for (int i = 0; i < 8; ++i) p2 += p2red[i];
    double c = (double)ws[OFF_C + w];
    double u2;
    gshd = expmap_scale(c, p2, &u2);
    ((double*)(ws + OFF_X2D2))[w] = u2;
  }
  __syncthreads();
  float g = (float)gshd;
  ws[OFF_TP + w * DIM + t] = g * a0;
  if (has2) ws[OFF_TP + w * DIM + t + 512] = g * a1;
}

extern "C" void kernel_launch(void* const* d_in, const int* in_sizes, int n_in,
                              void* d_out, int out_size, void* d_ws, size_t ws_size,
                              hipStream_t stream) {
  (void)in_sizes; (void)n_in; (void)out_size; (void)ws_size;
  const float* shot = (const float*)d_in[0];
  const float* qry  = (const float*)d_in[1];
  const float* W1   = (const float*)d_in[2];
  const float* b1   = (const float*)d_in[3];
  const float* W2   = (const float*)d_in[4];
  const float* b2   = (const float*)d_in[5];
  const float* W3   = (const float*)d_in[6];
  const float* b3   = (const float*)d_in[7];
  const float* Wr1  = (const float*)d_in[8];
  const float* br1  = (const float*)d_in[9];
  const float* Wr2  = (const float*)d_in[10];
  const float* br2  = (const float*)d_in[11];
  float* ws = (float*)d_ws;
  float* out = (float*)d_out;
  int* nidx = (int*)(ws + OFF_NIDX);

  void* args[] = {
    (void*)&shot, (void*)&qry,
    (void*)&W1, (void*)&b1, (void*)&W2, (void*)&b2, (void*)&W3, (void*)&b3,
    (void*)&Wr1, (void*)&br1, (void*)&Wr2, (void*)&br2,
    (void*)&ws, (void*)&out
  };
  hipError_t err = hipLaunchCooperativeKernel((const void*)k_mega, dim3(256), dim3(256),
                                              args, 0, stream);
  if (err != hipSuccess) {
    // fallback: proven 6-kernel path (R6)
    hipLaunchKernelGGL(k_fuse1,    dim3(128), dim3(640), 0, stream, qry, shot, ws);
    hipLaunchKernelGGL(k_ctrl,     dim3(32), dim3(512), 0, stream, W1, b1, W2, b2, W3, b3, ws);
    hipLaunchKernelGGL(k_gemmdist, dim3(256), dim3(256), 0, stream, ws + OFF_XVEC, qry, ws, 0, out);
    hipLaunchKernelGGL(k_topk,     dim3(32), dim3(1024), 0, stream, ws, nidx);
    hipLaunchKernelGGL(k_reftmp,   dim3(32), dim3(512), 0, stream, qry, Wr1, br1, Wr2, br2, ws, nidx);
    hipLaunchKernelGGL(k_gemmdist, dim3(256), dim3(256), 0, stream, ws + OFF_TP, qry, ws, 1, out);
  }
}

// Round 9
// 134.604 us; speedup vs baseline: 1.8479x; 1.8479x over previous
//
#include <hip/hip_runtime.h>
#include <math.h>

#define NSHOT 5
#define WAY 32
#define DIM 640
#define NQ 4096
#define RNEAR 10

// ---- workspace layout (float offsets) — R6-proven footprint ----
constexpr int OFF_PROTOS = 0;        // 32*640
constexpr int OFF_QPART  = 20480;    // 128*640 column partial sums (incl. shot fold)
constexpr int OFF_C      = 102400;   // 32
constexpr int OFF_XVEC   = 102432;   // 32*640 (proto_p)
constexpr int OFF_DIS    = 122912;   // 32*4096
constexpr int OFF_S      = 253984;   // 32
constexpr int OFF_U      = 254016;   // 32
constexpr int OFF_NID    = 254048;   // 32*10
constexpr int OFF_TP     = 254368;   // 32*640 (test_proto)
constexpr int OFF_NIDX   = 274848;   // 32*10 ints
constexpr int OFF_Q2D    = 275200;   // double[4096]
constexpr int OFF_X2D    = 283392;   // double[32] (proto_p norms^2)
constexpr int OFF_X2D2   = 283456;   // double[32] (test_proto norms^2)

__device__ __forceinline__ double wave_sum_d(double v) {
#pragma unroll
  for (int o = 32; o > 0; o >>= 1) v += __shfl_down(v, o, 64);
  return v;
}

__device__ __forceinline__ double dist_hyp(double c, double xdotq, double u2, double q2) {
  const double EPSd = 1e-5;
  double sc = sqrt(c);
  double nq = sqrt(q2);
  double nf = fmax(nq, EPSd);
  double th = tanh(sc * nf);
  double al = th / (sc * nf);
  double ny = fmax(al * nq, EPSd);
  double mx = 0.999 / sc;
  if (ny > mx) al *= mx / ny;
  double y2 = al * al * q2;
  double uy = -al * xdotq;
  double A = 1.0 + 2.0 * c * uy + c * y2;
  double B = 1.0 - c * u2;
  double den = fmax(1.0 + 2.0 * c * uy + c * c * u2 * y2, EPSd);
  double num2 = fmax(A * A * u2 + 2.0 * A * B * uy + B * B * y2, 0.0);
  double n = sqrt(num2) / den;
  double arg = sc * n;
  const double CLIP = (double)(1.0f - 1e-5f);
  arg = fmin(fmax(arg, 0.0), CLIP);
  return (1.0 / sc) * log((1.0 + arg) / (1.0 - arg));
}

__device__ __forceinline__ double expmap_scale(double c, double p2, double* u2out) {
  double sc = sqrt(c);
  double ntrue = sqrt(p2);
  double nf = fmax(ntrue, 1e-5);
  double th = tanh(sc * nf);
  double s0 = th / (sc * nf);
  double ny = fmax(s0 * ntrue, 1e-5);
  double mx = 0.999 / sc;
  if (ny > mx) s0 *= mx / ny;
  *u2out = s0 * s0 * p2;
  return s0;
}

// grid 128 x 640thr: protos (b<32), per-row q2 (f64), QPART rows (Q cols + shot fold)
__global__ __launch_bounds__(640) void k_fuse1(const float* __restrict__ Qm,
                                               const float* __restrict__ shot, float* ws) {
  __shared__ double q2w[32][10];
  int b = blockIdx.x, t = threadIdx.x;
  int lane = t & 63, wid = t >> 6;  // 10 waves
  float protoval = 0.f;
  if (b < WAY) {
    float s = 0.f;
#pragma unroll
    for (int s5 = 0; s5 < NSHOT; ++s5) s += shot[(size_t)(s5 * WAY + b) * DIM + t];
    protoval = s * 0.2f;
    ws[OFF_PROTOS + b * DIM + t] = protoval;
  }
  int r0 = b * 32;
  float colacc = 0.f;
  for (int r = 0; r < 32; ++r) {
    float v = Qm[(size_t)(r0 + r) * DIM + t];
    colacc += v;
    double sq = (double)v * v;
    sq = wave_sum_d(sq);
    if (lane == 0) q2w[r][wid] = sq;
  }
  ws[OFF_QPART + b * DIM + t] = colacc + 5.f * protoval;  // shot contribution folded in
  __syncthreads();
  if (t < 32) {
    double s = 0.0;
#pragma unroll
    for (int k = 0; k < 10; ++k) s += q2w[t][k];
    ((double*)(ws + OFF_Q2D))[r0 + t] = s;
  }
}

// controller MLP, 512 threads: parallel float4 am-reduction + float4 W1 GEMM
__global__ __launch_bounds__(512) void k_ctrl(const float* __restrict__ W1, const float* __restrict__ b1,
                                              const float* __restrict__ W2, const float* __restrict__ b2,
                                              const float* __restrict__ W3, const float* __restrict__ b3,
                                              float* ws) {
  __shared__ float cat[2 * DIM];           // [pr | am]
  __shared__ float4 ampart[3][160];
  __shared__ float h1p[16][128];
  __shared__ float h1s[128];
  __shared__ float h2p[8][64], h2s[64];
  __shared__ float lg[5];
  __shared__ double redd[8];
  __shared__ double sBeta;
  int w = blockIdx.x, t = threadIdx.x;
  int lane = t & 63, wid = t >> 6;   // 8 waves
  double ps = 0.0;
  for (int d = t; d < DIM; d += 512) {
    float v = ws[OFF_PROTOS + w * DIM + d];
    cat[d] = v; ps += (double)v * v;
  }
  ps = wave_sum_d(ps);
  if (lane == 0) redd[wid] = ps;
  // am partials: 3 p-slices x 160 column-quads, independent float4 accumulation
  if (t < 480) {
    int s = t / 160, quad = t - s * 160;
    int p0 = s * 43, p1 = (s == 2) ? 128 : (p0 + 43);
    float4 a = {0.f, 0.f, 0.f, 0.f};
#pragma unroll 4
    for (int p = p0; p < p1; ++p) {
      float4 v = *(const float4*)&ws[OFF_QPART + p * DIM + quad * 4];
      a.x += v.x; a.y += v.y; a.z += v.z; a.w += v.w;
    }
    ampart[s][quad] = a;
  }
  __syncthreads();
  if (t < 160) {
    float4 a = ampart[0][t], b4 = ampart[1][t], c4 = ampart[2][t];
    float4 r;
    r.x = (a.x + b4.x + c4.x) / 4256.f;
    r.y = (a.y + b4.y + c4.y) / 4256.f;
    r.z = (a.z + b4.z + c4.z) / 4256.f;
    r.w = (a.w + b4.w + c4.w) / 4256.f;
    *(float4*)&cat[DIM + t * 4] = r;
  }
  __syncthreads();
  // H1: thread = (4-neuron group ng, 80-k slice ks); float4 W1 loads
  {
    int ng = t & 31, ks = t >> 5;
    int k0 = ks * 80;
    float4 acc = {0.f, 0.f, 0.f, 0.f};
#pragma unroll 8
    for (int k = k0; k < k0 + 80; ++k) {
      float4 wr = *(const float4*)&W1[(size_t)k * 128 + ng * 4];
      float xv = cat[k];
      acc.x = fmaf(xv, wr.x, acc.x);
      acc.y = fmaf(xv, wr.y, acc.y);
      acc.z = fmaf(xv, wr.z, acc.z);
      acc.w = fmaf(xv, wr.w, acc.w);
    }
    *(float4*)&h1p[ks][ng * 4] = acc;
  }
  __syncthreads();
  if (t < 128) {
    float a = b1[t];
#pragma unroll
    for (int s = 0; s < 16; ++s) a += h1p[s][t];
    h1s[t] = fmaxf(a, 0.f);
  }
  __syncthreads();
  {
    int n = t & 63, s2 = t >> 6;   // 8 slices x 16 k
    int k0 = s2 * 16;
    float acc = 0.f;
#pragma unroll
    for (int k = 0; k < 16; ++k) acc = fmaf(h1s[k0 + k], W2[(size_t)(k0 + k) * 64 + n], acc);
    h2p[s2][n] = acc;
  }
  __syncthreads();
  if (t < 64) {
    float a = b2[t];
#pragma unroll
    for (int s = 0; s < 8; ++s) a += h2p[s][t];
    h2s[t] = fmaxf(a, 0.f);
  }
  __syncthreads();
  if (t < 5) {
    float a = b3[t];
    for (int k = 0; k < 64; ++k) a = fmaf(h2s[k], W3[k * 5 + t], a);
    lg[t] = a;
  }
  __syncthreads();
  if (t == 0) {
    double p2 = 0.0;
    for (int i = 0; i < 8; ++i) p2 += redd[i];
    double m = lg[0];
    for (int i = 1; i < 5; ++i) m = fmax(m, (double)lg[i]);
    double se = 0.0, cv = 0.0;
    for (int i = 0; i < 5; ++i) { double e = exp((double)lg[i] - m); se += e; cv += e * 0.2 * (double)(i + 1); }
    double c = cv / se;
    ws[OFF_C + w] = (float)c;
    double u2;
    sBeta = expmap_scale(c, p2, &u2);
    ((double*)(ws + OFF_X2D))[w] = u2;
  }
  __syncthreads();
  float beta = (float)sBeta;
  for (int d = t; d < DIM; d += 512) ws[OFF_XVEC + w * DIM + d] = beta * cat[d];
}

// full-K GEMM, grid 256 x 128 thr, thread tile 2q x 2w: (q,q+8) x (w,w+16); fused f64 dist
__global__ __launch_bounds__(128) void k_gemmdist(const float* __restrict__ X, const float* __restrict__ Qm,
                                                  float* __restrict__ ws, int mode, float* __restrict__ out) {
  __shared__ float Qs[2][16][68];
  __shared__ float Xs[2][32][68];
  int t = threadIdx.x;
  int q0 = blockIdx.x * 16;
  int rhi = t >> 4, cq = t & 15;          // staging: rows rhi, rhi+8, ... ; col quad cq
  const float* qb0 = Qm + (size_t)(q0 + rhi) * DIM + cq * 4;
  const float* xb0 = X + (size_t)rhi * DIM + cq * 4;
  float4 pf[6];
  // prefetch chunk 0
#pragma unroll
  for (int i = 0; i < 2; ++i) pf[i] = *(const float4*)(qb0 + (size_t)(i * 8) * DIM);
#pragma unroll
  for (int i = 0; i < 4; ++i) pf[2 + i] = *(const float4*)(xb0 + (size_t)(i * 8) * DIM);
#pragma unroll
  for (int i = 0; i < 2; ++i) *(float4*)&Qs[0][i * 8 + rhi][cq * 4] = pf[i];
#pragma unroll
  for (int i = 0; i < 4; ++i) *(float4*)&Xs[0][i * 8 + rhi][cq * 4] = pf[2 + i];
  __syncthreads();
  int q = t & 7, wv = t >> 3;             // q-pair (q,q+8), w-pair (wv,wv+16)
  float a00 = 0.f, a01 = 0.f, a10 = 0.f, a11 = 0.f;
  for (int c = 0; c < 10; ++c) {
    int bsel = c & 1;
    if (c < 9) {
      size_t kc = (size_t)(c + 1) * 64;
#pragma unroll
      for (int i = 0; i < 2; ++i) pf[i] = *(const float4*)(qb0 + (size_t)(i * 8) * DIM + kc);
#pragma unroll
      for (int i = 0; i < 4; ++i) pf[2 + i] = *(const float4*)(xb0 + (size_t)(i * 8) * DIM + kc);
    }
    const float* q0r = &Qs[bsel][q][0];
    const float* q1r = &Qs[bsel][q + 8][0];
    const float* x0r = &Xs[bsel][wv][0];
    const float* x1r = &Xs[bsel][wv + 16][0];
#pragma unroll
    for (int kk = 0; kk < 64; kk += 4) {
      float4 qa = *(const float4*)(q0r + kk);
      float4 qc = *(const float4*)(q1r + kk);
      float4 xa = *(const float4*)(x0r + kk);
      float4 xc = *(const float4*)(x1r + kk);
      a00 = fmaf(qa.x, xa.x, a00); a00 = fmaf(qa.y, xa.y, a00); a00 = fmaf(qa.z, xa.z, a00); a00 = fmaf(qa.w, xa.w, a00);
      a01 = fmaf(qa.x, xc.x, a01); a01 = fmaf(qa.y, xc.y, a01); a01 = fmaf(qa.z, xc.z, a01); a01 = fmaf(qa.w, xc.w, a01);
      a10 = fmaf(qc.x, xa.x, a10); a10 = fmaf(qc.y, xa.y, a10); a10 = fmaf(qc.z, xa.z, a10); a10 = fmaf(qc.w, xa.w, a10);
      a11 = fmaf(qc.x, xc.x, a11); a11 = fmaf(qc.y, xc.y, a11); a11 = fmaf(qc.z, xc.z, a11); a11 = fmaf(qc.w, xc.w, a11);
    }
    if (c < 9) {
      __syncthreads();
      int nb = bsel ^ 1;
#pragma unroll
      for (int i = 0; i < 2; ++i) *(float4*)&Qs[nb][i * 8 + rhi][cq * 4] = pf[i];
#pragma unroll
      for (int i = 0; i < 4; ++i) *(float4*)&Xs[nb][i * 8 + rhi][cq * 4] = pf[2 + i];
      __syncthreads();
    }
  }
  const double* q2d   = (const double*)(ws + OFF_Q2D);
  const double* u2arr = (const double*)(ws + (mode ? OFF_X2D2 : OFF_X2D));
  int qq0 = q0 + q, qq1 = q0 + q + 8;
  double q2a = q2d[qq0], q2b = q2d[qq1];
  double c0 = (double)ws[OFF_C + wv], c1 = (double)ws[OFF_C + wv + 16];
  double u20 = u2arr[wv], u21 = u2arr[wv + 16];
  double d00 = dist_hyp(c0, (double)a00, u20, q2a);
  double d01 = dist_hyp(c1, (double)a01, u21, q2a);
  double d10 = dist_hyp(c0, (double)a10, u20, q2b);
  double d11 = dist_hyp(c1, (double)a11, u21, q2b);
  if (mode == 0) {
    ws[OFF_DIS + (size_t)wv * NQ + qq0]        = (float)d00;
    ws[OFF_DIS + (size_t)(wv + 16) * NQ + qq0] = (float)d01;
    ws[OFF_DIS + (size_t)wv * NQ + qq1]        = (float)d10;
    ws[OFF_DIS + (size_t)(wv + 16) * NQ + qq1] = (float)d11;
  } else {
    out[(size_t)qq0 * WAY + wv]      = (float)(-d00 / 16.0);
    out[(size_t)qq0 * WAY + wv + 16] = (float)(-d01 / 16.0);
    out[(size_t)qq1 * WAY + wv]      = (float)(-d10 / 16.0);
    out[(size_t)qq1 * WAY + wv + 16] = (float)(-d11 / 16.0);
  }
}

// per-way: row sum S, first-10-raw-col sum U, stable top-10. Register state only.
__global__ __launch_bounds__(1024) void k_topk(float* ws, int* nidx) {
  __shared__ double sredS[16], sredU[16];
  __shared__ float wv[16]; __shared__ int wi[16];
  __shared__ int swi;
  int w = blockIdx.x, t = threadIdx.x;
  int lane = t & 63, wid = t >> 6;
  const float* base = ws + OFF_DIS + (size_t)w * NQ;
  float v0 = base[t], v1 = base[1024 + t], v2 = base[2048 + t], v3 = base[3072 + t];
  unsigned tk = 0;
  double s = (double)v0 + (double)v1 + (double)v2 + (double)v3;
  double u = (t < RNEAR) ? (double)v0 : 0.0;
  s = wave_sum_d(s);
  u = wave_sum_d(u);
  if (lane == 0) { sredS[wid] = s; sredU[wid] = u; }
  __syncthreads();
  if (t == 0) {
    double S = 0.0, U = 0.0;
    for (int k = 0; k < 16; ++k) { S += sredS[k]; U += sredU[k]; }
    ws[OFF_S + w] = (float)S;
    ws[OFF_U + w] = (float)U;
  }
  for (int r = 0; r < RNEAR; ++r) {
    float lv = INFINITY; int li = 0x7fffffff;
    if (!(tk & 1u) && (v0 < lv || (v0 == lv && t < li)))        { lv = v0; li = t; }
    if (!(tk & 2u) && (v1 < lv || (v1 == lv && 1024 + t < li))) { lv = v1; li = 1024 + t; }
    if (!(tk & 4u) && (v2 < lv || (v2 == lv && 2048 + t < li))) { lv = v2; li = 2048 + t; }
    if (!(tk & 8u) && (v3 < lv || (v3 == lv && 3072 + t < li))) { lv = v3; li = 3072 + t; }
#pragma unroll
    for (int o = 32; o > 0; o >>= 1) {
      float ov = __shfl_down(lv, o, 64);
      int oi = __shfl_down(li, o, 64);
      if (ov < lv || (ov == lv && oi < li)) { lv = ov; li = oi; }
    }
    if (lane == 0) { wv[wid] = lv; wi[wid] = li; }
    __syncthreads();
    if (t < 64) {
      float bv = (lane < 16) ? wv[lane] : INFINITY;
      int bi = (lane < 16) ? wi[lane] : 0x7fffffff;
#pragma unroll
      for (int o = 8; o > 0; o >>= 1) {
        float ov = __shfl_down(bv, o, 64);
        int oi = __shfl_down(bi, o, 64);
        if (ov < bv || (ov == bv && oi < bi)) { bv = ov; bi = oi; }
      }
      if (lane == 0) {
        ws[OFF_NID + w * RNEAR + r] = bv;
        nidx[w * RNEAR + r] = bi;
        swi = bi;
      }
    }
    __syncthreads();
    int sw = swi;
    if ((sw & 1023) == t) tk |= 1u << (sw >> 10);
  }
}

// fused: per-way stats + refine MLP + tmp/expmap -> TP
__global__ __launch_bounds__(512) void k_reftmp(const float* __restrict__ Qm,
                                                const float* __restrict__ Wr1, const float* __restrict__ br1,
                                                const float* __restrict__ Wr2, const float* __restrict__ br2,
                                                float* ws, const int* __restrict__ nidx) {
  __shared__ float colsh[RNEAR][33];
  __shared__ float rr[22];
  __shared__ float qjNid[RNEAR];
  __shared__ int qj[RNEAR];
  __shared__ float Ssh[WAY], Ush[WAY];
  __shared__ float hr[RNEAR], iw[RNEAR];
  __shared__ float onw_sh;
  __shared__ double p2red[8];
  __shared__ double gshd;
  int w = blockIdx.x, t = threadIdx.x;
  int lane = t & 63, wid = t >> 6;
  if (t < WAY) { Ssh[t] = ws[OFF_S + t]; Ush[t] = ws[OFF_U + t]; }
  if (t >= 64 && t < 64 + RNEAR) {
    int j = t - 64;
    qj[j] = nidx[w * RNEAR + j];
    qjNid[j] = ws[OFF_NID + w * RNEAR + j];
  }
  __syncthreads();
  if (t < WAY * RNEAR) {
    int j = t >> 5, w2 = t & 31;
    colsh[j][w2] = ws[OFF_DIS + (size_t)w2 * NQ + qj[j]];
  }
  __syncthreads();
  if (t < RNEAR) {
    double cs = 0.0, pc = 0.0;
    for (int w2 = 0; w2 < WAY; ++w2) {
      float dv = colsh[t][w2];
      cs += dv;
      if (w2 < w) pc += dv;
    }
    rr[t] = qjNid[t];
    rr[RNEAR + t] = (float)((cs - qjNid[t]) / (double)(WAY - 1));
    colsh[t][32] = (float)pc;
  }
  __syncthreads();
  if (t == 0) {
    double sn = 0.0; for (int j = 0; j < RNEAR; ++j) sn += rr[j];
    double oi = ((double)Ssh[w] - sn) / (double)(NQ - RNEAR);
    double pref = 0.0; for (int j = 0; j < w; ++j) pref += Ssh[j];
    double suf = 0.0; for (int j = w + 1; j < WAY; ++j) suf += (double)Ssh[j] - (double)Ush[j];
    double spc = 0.0; for (int j = 0; j < RNEAR; ++j) spc += colsh[j][32];
    rr[20] = (float)oi;
    rr[21] = (float)((pref - spc + suf) / ((double)(WAY - 1) * (double)(NQ - RNEAR)));
  }
  __syncthreads();
  if (t < RNEAR) {
    float a = br1[t];
    for (int k = 0; k < 22; ++k) a = fmaf(rr[k], Wr1[k * RNEAR + t], a);
    hr[t] = fmaxf(a, 0.f);
  }
  __syncthreads();
  if (t == 0) {
    double o[11];
    for (int r2 = 0; r2 < 11; ++r2) {
      float a = br2[r2];
      for (int k = 0; k < RNEAR; ++k) a = fmaf(hr[k], Wr2[k * 11 + r2], a);
      o[r2] = a;
    }
    double m = o[0]; for (int i = 1; i < RNEAR; ++i) m = fmax(m, o[i]);
    double se = 0.0; double e[RNEAR];
    for (int i = 0; i < RNEAR; ++i) { e[i] = exp(o[i] - m); se += e[i]; }
    for (int i = 0; i < RNEAR; ++i) iw[i] = (float)(e[i] / se);
    onw_sh = (float)(1.0 / (1.0 + exp(-o[10])));
  }
  __syncthreads();
  float onwv = onw_sh;
  float a0 = 0.f, a1 = 0.f;
  bool has2 = (t + 512 < DIM);
  double ls = 0.0;
  {
    int d = t;
    float wd = 0.f;
#pragma unroll
    for (int j = 0; j < RNEAR; ++j) wd = fmaf(Qm[(size_t)qj[j] * DIM + d], iw[j], wd);
    a0 = ws[OFF_PROTOS + w * DIM + d] * onwv + wd * (1.f - onwv);
    ls += (double)a0 * a0;
  }
  if (has2) {
    int d = t + 512;
    float wd = 0.f;
#pragma unroll
    for (int j = 0; j < RNEAR; ++j) wd = fmaf(Qm[(size_t)qj[j] * DIM + d], iw[j], wd);
    a1 = ws[OFF_PROTOS + w * DIM + d] * onwv + wd * (1.f - onwv);
    ls += (double)a1 * a1;
  }
  ls = wave_sum_d(ls);
  if (lane == 0) p2red[wid] = ls;
  __syncthreads();
  if (t == 0) {
    double p2 = 0.0;
    for (int i = 0; i < 8; ++i) p2 += p2red[i];
    double c = (double)ws[OFF_C + w];
    double u2;
    gshd = expmap_scale(c, p2, &u2);
    ((double*)(ws + OFF_X2D2))[w] = u2;
  }
  __syncthreads();
  float g = (float)gshd;
  ws[OFF_TP + w * DIM + t] = g * a0;
  if (has2) ws[OFF_TP + w * DIM + t + 512] = g * a1;
}

extern "C" void kernel_launch(void* const* d_in, const int* in_sizes, int n_in,
                              void* d_out, int out_size, void* d_ws, size_t ws_size,
                              hipStream_t stream) {
  (void)in_sizes; (void)n_in; (void)out_size; (void)ws_size;
  const float* shot = (const float*)d_in[0];
  const float* qry  = (const float*)d_in[1];
  const float* W1   = (const float*)d_in[2];
  const float* b1   = (const float*)d_in[3];
  const float* W2   = (const float*)d_in[4];
  const float* b2   = (const float*)d_in[5];
  const float* W3   = (const float*)d_in[6];
  const float* b3   = (const float*)d_in[7];
  const float* Wr1  = (const float*)d_in[8];
  const float* br1  = (const float*)d_in[9];
  const float* Wr2  = (const float*)d_in[10];
  const float* br2  = (const float*)d_in[11];
  float* ws = (float*)d_ws;
  float* out = (float*)d_out;
  int* nidx = (int*)(ws + OFF_NIDX);

  hipLaunchKernelGGL(k_fuse1,    dim3(128), dim3(640), 0, stream, qry, shot, ws);
  hipLaunchKernelGGL(k_ctrl,     dim3(32), dim3(512), 0, stream, W1, b1, W2, b2, W3, b3, ws);
  hipLaunchKernelGGL(k_gemmdist, dim3(256), dim3(128), 0, stream, ws + OFF_XVEC, qry, ws, 0, out);
  hipLaunchKernelGGL(k_topk,     dim3(32), dim3(1024), 0, stream, ws, nidx);
  hipLaunchKernelGGL(k_reftmp,   dim3(32), dim3(512), 0, stream, qry, Wr1, br1, Wr2, br2, ws, nidx);
  hipLaunchKernelGGL(k_gemmdist, dim3(256), dim3(128), 0, stream, ws + OFF_TP, qry, ws, 1, out);
}

// Round 10
// 85.719 us; speedup vs baseline: 2.9017x; 1.5703x over previous
//
#include <hip/hip_runtime.h>
#include <math.h>

#define NSHOT 5
#define WAY 32
#define DIM 640
#define NQ 4096
#define RNEAR 10

// ---- workspace layout (float offsets) — R6-proven footprint ----
constexpr int OFF_PROTOS = 0;        // 32*640
constexpr int OFF_QPART  = 20480;    // 128*640 column partial sums (incl. shot fold)
constexpr int OFF_C      = 102400;   // 32
constexpr int OFF_XVEC   = 102432;   // 32*640 (proto_p)
constexpr int OFF_DIS    = 122912;   // 32*4096
constexpr int OFF_S      = 253984;   // 32
constexpr int OFF_U      = 254016;   // 32
constexpr int OFF_NID    = 254048;   // 32*10
constexpr int OFF_TP     = 254368;   // 32*640 (test_proto)
constexpr int OFF_NIDX   = 274848;   // 32*10 ints
constexpr int OFF_Q2D    = 275200;   // double[4096]
constexpr int OFF_X2D    = 283392;   // double[32] (proto_p norms^2)
constexpr int OFF_X2D2   = 283456;   // double[32] (test_proto norms^2)

__device__ __forceinline__ double wave_sum_d(double v) {
#pragma unroll
  for (int o = 32; o > 0; o >>= 1) v += __shfl_down(v, o, 64);
  return v;
}

__device__ __forceinline__ double dist_hyp(double c, double xdotq, double u2, double q2) {
  const double EPSd = 1e-5;
  double sc = sqrt(c);
  double nq = sqrt(q2);
  double nf = fmax(nq, EPSd);
  double th = tanh(sc * nf);
  double al = th / (sc * nf);
  double ny = fmax(al * nq, EPSd);
  double mx = 0.999 / sc;
  if (ny > mx) al *= mx / ny;
  double y2 = al * al * q2;
  double uy = -al * xdotq;
  double A = 1.0 + 2.0 * c * uy + c * y2;
  double B = 1.0 - c * u2;
  double den = fmax(1.0 + 2.0 * c * uy + c * c * u2 * y2, EPSd);
  double num2 = fmax(A * A * u2 + 2.0 * A * B * uy + B * B * y2, 0.0);
  double n = sqrt(num2) / den;
  double arg = sc * n;
  const double CLIP = (double)(1.0f - 1e-5f);
  arg = fmin(fmax(arg, 0.0), CLIP);
  return (1.0 / sc) * log((1.0 + arg) / (1.0 - arg));
}

__device__ __forceinline__ double expmap_scale(double c, double p2, double* u2out) {
  double sc = sqrt(c);
  double ntrue = sqrt(p2);
  double nf = fmax(ntrue, 1e-5);
  double th = tanh(sc * nf);
  double s0 = th / (sc * nf);
  double ny = fmax(s0 * ntrue, 1e-5);
  double mx = 0.999 / sc;
  if (ny > mx) s0 *= mx / ny;
  *u2out = s0 * s0 * p2;
  return s0;
}

// grid 128 x 640thr: protos (b<32), per-row q2 (f64), QPART rows (Q cols + shot fold)
__global__ __launch_bounds__(640) void k_fuse1(const float* __restrict__ Qm,
                                               const float* __restrict__ shot, float* ws) {
  __shared__ double q2w[32][10];
  int b = blockIdx.x, t = threadIdx.x;
  int lane = t & 63, wid = t >> 6;  // 10 waves
  float protoval = 0.f;
  if (b < WAY) {
    float s = 0.f;
#pragma unroll
    for (int s5 = 0; s5 < NSHOT; ++s5) s += shot[(size_t)(s5 * WAY + b) * DIM + t];
    protoval = s * 0.2f;
    ws[OFF_PROTOS + b * DIM + t] = protoval;
  }
  int r0 = b * 32;
  float colacc = 0.f;
  for (int r = 0; r < 32; ++r) {
    float v = Qm[(size_t)(r0 + r) * DIM + t];
    colacc += v;
    double sq = (double)v * v;
    sq = wave_sum_d(sq);
    if (lane == 0) q2w[r][wid] = sq;
  }
  ws[OFF_QPART + b * DIM + t] = colacc + 5.f * protoval;  // shot contribution folded in
  __syncthreads();
  if (t < 32) {
    double s = 0.0;
#pragma unroll
    for (int k = 0; k < 10; ++k) s += q2w[t][k];
    ((double*)(ws + OFF_Q2D))[r0 + t] = s;
  }
}

// controller MLP, 512 threads: parallel float4 am-reduction + float4 W1 GEMM
__global__ __launch_bounds__(512) void k_ctrl(const float* __restrict__ W1, const float* __restrict__ b1,
                                              const float* __restrict__ W2, const float* __restrict__ b2,
                                              const float* __restrict__ W3, const float* __restrict__ b3,
                                              float* ws) {
  __shared__ float cat[2 * DIM];           // [pr | am]
  __shared__ float4 ampart[3][160];
  __shared__ float h1p[16][128];
  __shared__ float h1s[128];
  __shared__ float h2p[8][64], h2s[64];
  __shared__ float lg[5];
  __shared__ double redd[8];
  __shared__ double sBeta;
  int w = blockIdx.x, t = threadIdx.x;
  int lane = t & 63, wid = t >> 6;   // 8 waves
  double ps = 0.0;
  for (int d = t; d < DIM; d += 512) {
    float v = ws[OFF_PROTOS + w * DIM + d];
    cat[d] = v; ps += (double)v * v;
  }
  ps = wave_sum_d(ps);
  if (lane == 0) redd[wid] = ps;
  if (t < 480) {
    int s = t / 160, quad = t - s * 160;
    int p0 = s * 43, p1 = (s == 2) ? 128 : (p0 + 43);
    float4 a = {0.f, 0.f, 0.f, 0.f};
#pragma unroll 4
    for (int p = p0; p < p1; ++p) {
      float4 v = *(const float4*)&ws[OFF_QPART + p * DIM + quad * 4];
      a.x += v.x; a.y += v.y; a.z += v.z; a.w += v.w;
    }
    ampart[s][quad] = a;
  }
  __syncthreads();
  if (t < 160) {
    float4 a = ampart[0][t], b4 = ampart[1][t], c4 = ampart[2][t];
    float4 r;
    r.x = (a.x + b4.x + c4.x) / 4256.f;
    r.y = (a.y + b4.y + c4.y) / 4256.f;
    r.z = (a.z + b4.z + c4.z) / 4256.f;
    r.w = (a.w + b4.w + c4.w) / 4256.f;
    *(float4*)&cat[DIM + t * 4] = r;
  }
  __syncthreads();
  {
    int ng = t & 31, ks = t >> 5;
    int k0 = ks * 80;
    float4 acc = {0.f, 0.f, 0.f, 0.f};
#pragma unroll 8
    for (int k = k0; k < k0 + 80; ++k) {
      float4 wr = *(const float4*)&W1[(size_t)k * 128 + ng * 4];
      float xv = cat[k];
      acc.x = fmaf(xv, wr.x, acc.x);
      acc.y = fmaf(xv, wr.y, acc.y);
      acc.z = fmaf(xv, wr.z, acc.z);
      acc.w = fmaf(xv, wr.w, acc.w);
    }
    *(float4*)&h1p[ks][ng * 4] = acc;
  }
  __syncthreads();
  if (t < 128) {
    float a = b1[t];
#pragma unroll
    for (int s = 0; s < 16; ++s) a += h1p[s][t];
    h1s[t] = fmaxf(a, 0.f);
  }
  __syncthreads();
  {
    int n = t & 63, s2 = t >> 6;
    int k0 = s2 * 16;
    float acc = 0.f;
#pragma unroll
    for (int k = 0; k < 16; ++k) acc = fmaf(h1s[k0 + k], W2[(size_t)(k0 + k) * 64 + n], acc);
    h2p[s2][n] = acc;
  }
  __syncthreads();
  if (t < 64) {
    float a = b2[t];
#pragma unroll
    for (int s = 0; s < 8; ++s) a += h2p[s][t];
    h2s[t] = fmaxf(a, 0.f);
  }
  __syncthreads();
  if (t < 5) {
    float a = b3[t];
    for (int k = 0; k < 64; ++k) a = fmaf(h2s[k], W3[k * 5 + t], a);
    lg[t] = a;
  }
  __syncthreads();
  if (t == 0) {
    double p2 = 0.0;
    for (int i = 0; i < 8; ++i) p2 += redd[i];
    double m = lg[0];
    for (int i = 1; i < 5; ++i) m = fmax(m, (double)lg[i]);
    double se = 0.0, cv = 0.0;
    for (int i = 0; i < 5; ++i) { double e = exp((double)lg[i] - m); se += e; cv += e * 0.2 * (double)(i + 1); }
    double c = cv / se;
    ws[OFF_C + w] = (float)c;
    double u2;
    sBeta = expmap_scale(c, p2, &u2);
    ((double*)(ws + OFF_X2D))[w] = u2;
  }
  __syncthreads();
  float beta = (float)sBeta;
  for (int d = t; d < DIM; d += 512) ws[OFF_XVEC + w * DIM + d] = beta * cat[d];
}

// full-K GEMM: grid 512 (8q each) x 256 thr, one output/thread (q=t&7, w=t>>3).
// 2 blocks/CU x 4 waves = 8 waves/CU; LDS reads are 8-address broadcasts, conflict-free.
__global__ __launch_bounds__(256) void k_gemmdist(const float* __restrict__ X, const float* __restrict__ Qm,
                                                  float* __restrict__ ws, int mode, float* __restrict__ out) {
  __shared__ float S[2][40][68];   // rows 0..7 = Q, rows 8..39 = X
  int t = threadIdx.x;
  int q0 = blockIdx.x * 8;
  // staging: 640 float4 slots (40 rows x 16 quads); thread t -> slots t, t+256, (t+512 if t<128)
  int rowA = t >> 4, quadA = t & 15;
  int rowB = (t + 256) >> 4;          // 16..31 -> X rows 8..23
  int rowC = (t + 512) >> 4;          // 32..39 -> X rows 24..31
  bool hasC = (t < 128);
  const float* srcA = (rowA < 8 ? Qm + (size_t)(q0 + rowA) * DIM : X + (size_t)(rowA - 8) * DIM) + quadA * 4;
  const float* srcB = X + (size_t)(rowB - 8) * DIM + quadA * 4;
  const float* srcC = X + (size_t)(rowC - 8) * DIM + quadA * 4;
  float4 pA = *(const float4*)srcA;
  float4 pB = *(const float4*)srcB;
  float4 pC = {0.f, 0.f, 0.f, 0.f};
  if (hasC) pC = *(const float4*)srcC;
  *(float4*)&S[0][rowA][quadA * 4] = pA;
  *(float4*)&S[0][rowB][quadA * 4] = pB;
  if (hasC) *(float4*)&S[0][rowC][quadA * 4] = pC;
  __syncthreads();
  int q = t & 7, w = t >> 3;
  float ax = 0.f, ay = 0.f, az = 0.f, aw = 0.f;   // 4 independent FMA chains
  for (int c = 0; c < 10; ++c) {
    int bsel = c & 1;
    if (c < 9) {
      size_t kc = (size_t)(c + 1) * 64;
      pA = *(const float4*)(srcA + kc);
      pB = *(const float4*)(srcB + kc);
      if (hasC) pC = *(const float4*)(srcC + kc);
    }
    const float* qr = &S[bsel][q][0];
    const float* xr = &S[bsel][8 + w][0];
#pragma unroll
    for (int kk = 0; kk < 64; kk += 4) {
      float4 qv = *(const float4*)(qr + kk);
      float4 xv = *(const float4*)(xr + kk);
      ax = fmaf(qv.x, xv.x, ax);
      ay = fmaf(qv.y, xv.y, ay);
      az = fmaf(qv.z, xv.z, az);
      aw = fmaf(qv.w, xv.w, aw);
    }
    if (c < 9) {
      __syncthreads();
      int nb = bsel ^ 1;
      *(float4*)&S[nb][rowA][quadA * 4] = pA;
      *(float4*)&S[nb][rowB][quadA * 4] = pB;
      if (hasC) *(float4*)&S[nb][rowC][quadA * 4] = pC;
      __syncthreads();
    }
  }
  float acc = (ax + ay) + (az + aw);
  const double* q2d   = (const double*)(ws + OFF_Q2D);
  const double* u2arr = (const double*)(ws + (mode ? OFF_X2D2 : OFF_X2D));
  int qq = q0 + q;
  double d = dist_hyp((double)ws[OFF_C + w], (double)acc, u2arr[w], q2d[qq]);
  if (mode == 0) {
    ws[OFF_DIS + (size_t)w * NQ + qq] = (float)d;
  } else {
    out[(size_t)qq * WAY + w] = (float)(-d / 16.0);
  }
}

// per-way: row sum S, first-10-raw-col sum U, stable top-10. Register state only.
__global__ __launch_bounds__(1024) void k_topk(float* ws, int* nidx) {
  __shared__ double sredS[16], sredU[16];
  __shared__ float wv[16]; __shared__ int wi[16];
  __shared__ int swi;
  int w = blockIdx.x, t = threadIdx.x;
  int lane = t & 63, wid = t >> 6;
  const float* base = ws + OFF_DIS + (size_t)w * NQ;
  float v0 = base[t], v1 = base[1024 + t], v2 = base[2048 + t], v3 = base[3072 + t];
  unsigned tk = 0;
  double s = (double)v0 + (double)v1 + (double)v2 + (double)v3;
  double u = (t < RNEAR) ? (double)v0 : 0.0;
  s = wave_sum_d(s);
  u = wave_sum_d(u);
  if (lane == 0) { sredS[wid] = s; sredU[wid] = u; }
  __syncthreads();
  if (t == 0) {
    double S = 0.0, U = 0.0;
    for (int k = 0; k < 16; ++k) { S += sredS[k]; U += sredU[k]; }
    ws[OFF_S + w] = (float)S;
    ws[OFF_U + w] = (float)U;
  }
  for (int r = 0; r < RNEAR; ++r) {
    float lv = INFINITY; int li = 0x7fffffff;
    if (!(tk & 1u) && (v0 < lv || (v0 == lv && t < li)))        { lv = v0; li = t; }
    if (!(tk & 2u) && (v1 < lv || (v1 == lv && 1024 + t < li))) { lv = v1; li = 1024 + t; }
    if (!(tk & 4u) && (v2 < lv || (v2 == lv && 2048 + t < li))) { lv = v2; li = 2048 + t; }
    if (!(tk & 8u) && (v3 < lv || (v3 == lv && 3072 + t < li))) { lv = v3; li = 3072 + t; }
#pragma unroll
    for (int o = 32; o > 0; o >>= 1) {
      float ov = __shfl_down(lv, o, 64);
      int oi = __shfl_down(li, o, 64);
      if (ov < lv || (ov == lv && oi < li)) { lv = ov; li = oi; }
    }
    if (lane == 0) { wv[wid] = lv; wi[wid] = li; }
    __syncthreads();
    if (t < 64) {
      float bv = (lane < 16) ? wv[lane] : INFINITY;
      int bi = (lane < 16) ? wi[lane] : 0x7fffffff;
#pragma unroll
      for (int o = 8; o > 0; o >>= 1) {
        float ov = __shfl_down(bv, o, 64);
        int oi = __shfl_down(bi, o, 64);
        if (ov < bv || (ov == bv && oi < bi)) { bv = ov; bi = oi; }
      }
      if (lane == 0) {
        ws[OFF_NID + w * RNEAR + r] = bv;
        nidx[w * RNEAR + r] = bi;
        swi = bi;
      }
    }
    __syncthreads();
    int sw = swi;
    if ((sw & 1023) == t) tk |= 1u << (sw >> 10);
  }
}

// fused: per-way stats + refine MLP + tmp/expmap -> TP
__global__ __launch_bounds__(512) void k_reftmp(const float* __restrict__ Qm,
                                                const float* __restrict__ Wr1, const float* __restrict__ br1,
                                                const float* __restrict__ Wr2, const float* __restrict__ br2,
                                                float* ws, const int* __restrict__ nidx) {
  __shared__ float colsh[RNEAR][33];
  __shared__ float rr[22];
  __shared__ float qjNid[RNEAR];
  __shared__ int qj[RNEAR];
  __shared__ float Ssh[WAY], Ush[WAY];
  __shared__ float hr[RNEAR], iw[RNEAR];
  __shared__ float onw_sh;
  __shared__ double p2red[8];
  __shared__ double gshd;
  int w = blockIdx.x, t = threadIdx.x;
  int lane = t & 63, wid = t >> 6;
  if (t < WAY) { Ssh[t] = ws[OFF_S + t]; Ush[t] = ws[OFF_U + t]; }
  if (t >= 64 && t < 64 + RNEAR) {
    int j = t - 64;
    qj[j] = nidx[w * RNEAR + j];
    qjNid[j] = ws[OFF_NID + w * RNEAR + j];
  }
  __syncthreads();
  if (t < WAY * RNEAR) {
    int j = t >> 5, w2 = t & 31;
    colsh[j][w2] = ws[OFF_DIS + (size_t)w2 * NQ + qj[j]];
  }
  __syncthreads();
  if (t < RNEAR) {
    double cs = 0.0, pc = 0.0;
    for (int w2 = 0; w2 < WAY; ++w2) {
      float dv = colsh[t][w2];
      cs += dv;
      if (w2 < w) pc += dv;
    }
    rr[t] = qjNid[t];
    rr[RNEAR + t] = (float)((cs - qjNid[t]) / (double)(WAY - 1));
    colsh[t][32] = (float)pc;
  }
  __syncthreads();
  if (t == 0) {
    double sn = 0.0; for (int j = 0; j < RNEAR; ++j) sn += rr[j];
    double oi = ((double)Ssh[w] - sn) / (double)(NQ - RNEAR);
    double pref = 0.0; for (int j = 0; j < w; ++j) pref += Ssh[j];
    double suf = 0.0; for (int j = w + 1; j < WAY; ++j) suf += (double)Ssh[j] - (double)Ush[j];
    double spc = 0.0; for (int j = 0; j < RNEAR; ++j) spc += colsh[j][32];
    rr[20] = (float)oi;
    rr[21] = (float)((pref - spc + suf) / ((double)(WAY - 1) * (double)(NQ - RNEAR)));
  }
  __syncthreads();
  if (t < RNEAR) {
    float a = br1[t];
    for (int k = 0; k < 22; ++k) a = fmaf(rr[k], Wr1[k * RNEAR + t], a);
    hr[t] = fmaxf(a, 0.f);
  }
  __syncthreads();
  if (t == 0) {
    double o[11];
    for (int r2 = 0; r2 < 11; ++r2) {
      float a = br2[r2];
      for (int k = 0; k < RNEAR; ++k) a = fmaf(hr[k], Wr2[k * 11 + r2], a);
      o[r2] = a;
    }
    double m = o[0]; for (int i = 1; i < RNEAR; ++i) m = fmax(m, o[i]);
    double se = 0.0; double e[RNEAR];
    for (int i = 0; i < RNEAR; ++i) { e[i] = exp(o[i] - m); se += e[i]; }
    for (int i = 0; i < RNEAR; ++i) iw[i] = (float)(e[i] / se);
    onw_sh = (float)(1.0 / (1.0 + exp(-o[10])));
  }
  __syncthreads();
  float onwv = onw_sh;
  float a0 = 0.f, a1 = 0.f;
  bool has2 = (t + 512 < DIM);
  double ls = 0.0;
  {
    int d = t;
    float wd = 0.f;
#pragma unroll
    for (int j = 0; j < RNEAR; ++j) wd = fmaf(Qm[(size_t)qj[j] * DIM + d], iw[j], wd);
    a0 = ws[OFF_PROTOS + w * DIM + d] * onwv + wd * (1.f - onwv);
    ls += (double)a0 * a0;
  }
  if (has2) {
    int d = t + 512;
    float wd = 0.f;
#pragma unroll
    for (int j = 0; j < RNEAR; ++j) wd = fmaf(Qm[(size_t)qj[j] * DIM + d], iw[j], wd);
    a1 = ws[OFF_PROTOS + w * DIM + d] * onwv + wd * (1.f - onwv);
    ls += (double)a1 * a1;
  }
  ls = wave_sum_d(ls);
  if (lane == 0) p2red[wid] = ls;
  __syncthreads();
  if (t == 0) {
    double p2 = 0.0;
    for (int i = 0; i < 8; ++i) p2 += p2red[i];
    double c = (double)ws[OFF_C + w];
    double u2;
    gshd = expmap_scale(c, p2, &u2);
    ((double*)(ws + OFF_X2D2))[w] = u2;
  }
  __syncthreads();
  float g = (float)gshd;
  ws[OFF_TP + w * DIM + t] = g * a0;
  if (has2) ws[OFF_TP + w * DIM + t + 512] = g * a1;
}

extern "C" void kernel_launch(void* const* d_in, const int* in_sizes, int n_in,
                              void* d_out, int out_size, void* d_ws, size_t ws_size,
                              hipStream_t stream) {
  (void)in_sizes; (void)n_in; (void)out_size; (void)ws_size;
  const float* shot = (const float*)d_in[0];
  const float* qry  = (const float*)d_in[1];
  const float* W1   = (const float*)d_in[2];
  const float* b1   = (const float*)d_in[3];
  const float* W2   = (const float*)d_in[4];
  const float* b2   = (const float*)d_in[5];
  const float* W3   = (const float*)d_in[6];
  const float* b3   = (const float*)d_in[7];
  const float* Wr1  = (const float*)d_in[8];
  const float* br1  = (const float*)d_in[9];
  const float* Wr2  = (const float*)d_in[10];
  const float* br2  = (const float*)d_in[11];
  float* ws = (float*)d_ws;
  float* out = (float*)d_out;
  int* nidx = (int*)(ws + OFF_NIDX);

  hipLaunchKernelGGL(k_fuse1,    dim3(128), dim3(640), 0, stream, qry, shot, ws);
  hipLaunchKernelGGL(k_ctrl,     dim3(32), dim3(512), 0, stream, W1, b1, W2, b2, W3, b3, ws);
  hipLaunchKernelGGL(k_gemmdist, dim3(512), dim3(256), 0, stream, ws + OFF_XVEC, qry, ws, 0, out);
  hipLaunchKernelGGL(k_topk,     dim3(32), dim3(1024), 0, stream, ws, nidx);
  hipLaunchKernelGGL(k_reftmp,   dim3(32), dim3(512), 0, stream, qry, Wr1, br1, Wr2, br2, ws, nidx);
  hipLaunchKernelGGL(k_gemmdist, dim3(512), dim3(256), 0, stream, ws + OFF_TP, qry, ws, 1, out);
}